// Round 1
// baseline (65.641 us; speedup 1.0000x reference)
//
#include <hip/hip_runtime.h>

#define N_TIME 112
#define BATCH  262144
#define NV     (N_TIME / 4)   // 28 float4 per row

__device__ __forceinline__ float signal_eq(float cap, float c, float vp,
                                           float kd, float invT10) {
    const float TR   = 0.005f;
    const float R1   = 4.5f;
    const float SINA = 0.25881904510252074f;   // sin(15 deg)
    const float COSA = 0.96592582628906829f;   // cos(15 deg)
    float ct  = vp * cap + kd * c;             // tissue concentration
    float r1t = invT10 + R1 * ct;
    float e   = __expf(-TR * r1t);
    return (1.0f - e) * (20.0f * SINA) / (1.0f - e * COSA);
}

__global__ __launch_bounds__(256) void etofts_kernel(
    const float* __restrict__ ktrans_p,
    const float* __restrict__ vp_p,
    const float* __restrict__ ve_p,
    const float* __restrict__ T10_p,
    const float* __restrict__ cap_p,
    float* __restrict__ out_p)
{
    const int row = blockIdx.x * blockDim.x + threadIdx.x;
    if (row >= BATCH) return;

    const float DELTT = 4.0f / 60.0f;

    const float ktrans = ktrans_p[row];
    const float vp     = vp_p[row];
    const float ve     = ve_p[row];
    const float invT10 = 1.0f / T10_p[row];

    const float decay = __expf(-ktrans / ve * DELTT);
    const float kd    = ktrans * DELTT;

    const float4* cap = reinterpret_cast<const float4*>(cap_p) + (size_t)row * NV;
    float4*       out = reinterpret_cast<float4*>(out_p)       + (size_t)row * NV;

    float c = 0.0f;
    #pragma unroll 4
    for (int i = 0; i < NV; ++i) {
        float4 x = cap[i];
        float4 y;
        c = c * decay + x.x;  y.x = signal_eq(x.x, c, vp, kd, invT10);
        c = c * decay + x.y;  y.y = signal_eq(x.y, c, vp, kd, invT10);
        c = c * decay + x.z;  y.z = signal_eq(x.z, c, vp, kd, invT10);
        c = c * decay + x.w;  y.w = signal_eq(x.w, c, vp, kd, invT10);
        out[i] = y;
    }
}

extern "C" void kernel_launch(void* const* d_in, const int* in_sizes, int n_in,
                              void* d_out, int out_size, void* d_ws, size_t ws_size,
                              hipStream_t stream) {
    const float* ktrans = (const float*)d_in[0];
    const float* vp     = (const float*)d_in[1];
    const float* ve     = (const float*)d_in[2];
    const float* T10    = (const float*)d_in[3];
    const float* CAp    = (const float*)d_in[4];
    float* out = (float*)d_out;

    dim3 block(256);
    dim3 grid(BATCH / 256);
    etofts_kernel<<<grid, block, 0, stream>>>(ktrans, vp, ve, T10, CAp, out);
}